// Round 8
// baseline (399.018 us; speedup 1.0000x reference)
//
#include <hip/hip_runtime.h>
#include <math.h>

// Cyborg stack machine: B=256, S=128, V=512, H=30, N_STACKS=2, R=2, DEPTH=4
// All stack/peek/output vectors live in span{ones, init_vec, syms0..29} (32-dim).
// kA (R12): barrier-free split-f16 MFMA GEMM. A-fragments loaded DIRECTLY from
//   global x (frag layout row=m*16+(l&15), k=(l>>4)*8 is a contiguous 32B load);
//   register double-buffer; in-register row-norm reduce (swz16 + permlane32).
//   No LDS, no __syncthreads at all.
// kC (R12): R11 structure + v_permlane32_swap (VALU) replaces shfl_xor32 and
//   feeds pk0[m]/pk1[m] directly; norm 32-sum via sum16 DPP + 2 readlanes
//   (drops the 2 ds_swizzle xor16 from the critical path).

#define SS 128
#define VV 512
#define NROWS 208      // 8 pop + 8 pushop + 128 pushfn + 64 calc
#define ZOFF 1e-6f

// ws layout (float offsets)
#define OFF_I0   0                          // interp0: 32768*208
#define OFF_OC   (32768*208)                // out coords: 32768*32
#define OFF_GI   (OFF_OC + 32768*32)        // G[2][32][208]  (stack, basis, row)
#define OFF_M    (OFF_GI + 2*32*208)        // Gram 32*32
#define OFF_A    (OFF_M + 1024)             // A coef 208*3
#define OFF_Bc   (OFF_A + 624)              // B coef 208*3
#define OFF_W0   (OFF_Bc + 624)             // Wh/Wl f16: 2 x [208][512] halves

typedef _Float16 half8 __attribute__((ext_vector_type(8)));
typedef float f32x4 __attribute__((ext_vector_type(4)));

__device__ __forceinline__ float rlane(float v, int lane) {
    return __int_as_float(__builtin_amdgcn_readlane(__float_as_int(v), lane));
}
template <int CTRL>
__device__ __forceinline__ float dpp_add(float x) {
    int y = __builtin_amdgcn_update_dpp(0, __float_as_int(x), CTRL, 0xF, 0xF, true);
    return x + __int_as_float(y);
}
// full 16-lane row sum, result in all lanes of the row (pure VALU)
__device__ __forceinline__ float sum16(float x) {
    x = dpp_add<0xB1>(x);    // quad_perm [1,0,3,2]  (xor 1)
    x = dpp_add<0x4E>(x);    // quad_perm [2,3,0,1]  (xor 2)
    x = dpp_add<0x124>(x);   // row_ror:4
    x = dpp_add<0x128>(x);   // row_ror:8
    return x;
}
__device__ __forceinline__ float swz16(float x) {   // lane ^ 16 within 32-group (DS)
    return __int_as_float(__builtin_amdgcn_ds_swizzle(__float_as_int(x), 0x401F));
}
// v_permlane32_swap: lo[i] = x[i&31], hi[i] = x[32+(i&31)]  (pure VALU)
__device__ __forceinline__ void swap32(float x, float& lo, float& hi) {
    float a = x, b = x;
    asm("v_permlane32_swap_b32 %0, %1" : "+v"(a), "+v"(b));
    lo = a; hi = b;
}
__device__ __forceinline__ float xor32(float x) {   // x[lane^32] via permlane
    float lo, hi;
    swap32(x, lo, hi);
    return (threadIdx.x & 32) ? lo : hi;
}

__device__ __forceinline__ const float* w_row(int r, const float* pw, const float* pow_,
                                              const float* pfw, const float* cw) {
    if (r < 8)   return pw   + r * 1536;
    if (r < 16)  return pow_ + (r - 8) * 1536;
    if (r < 144) return pfw  + (r - 16) * 1536;
    return cw + (r - 144) * 1536;
}
__device__ __forceinline__ const float* nw_row(int r, const float* pn, const float* pon,
                                               const float* pfn, const float* cn) {
    if (r < 8)   return pn   + r * 3;
    if (r < 16)  return pon  + (r - 8) * 3;
    if (r < 144) return pfn  + (r - 16) * 3;
    return cn + (r - 144) * 3;
}

// ---------------- kernel B: precompute tables ----------------
__global__ void kB(const float* __restrict__ syms, const float* __restrict__ siv,
                   const float* __restrict__ pw, const float* __restrict__ pn,
                   const float* __restrict__ pow_, const float* __restrict__ pon,
                   const float* __restrict__ pfw, const float* __restrict__ pfn,
                   const float* __restrict__ cw, const float* __restrict__ cn,
                   float* __restrict__ ws) {
    int blk = blockIdx.x, tid = threadIdx.x;
    if (blk < 64) {
        // G[jj][e][c] = basis_e . w_row(c)[(jj+1)*512 ..)
        int jj = blk >> 5, e = blk & 31;
        __shared__ float bas[512];
        for (int i = tid; i < 512; i += 256)
            bas[i] = (e == 0) ? 1.0f : ((e == 1) ? siv[i] : syms[(e - 2) * 512 + i]);
        __syncthreads();
        if (tid < NROWS) {
            int c = tid;
            const float4* w4 = (const float4*)(w_row(c, pw, pow_, pfw, cw) + (jj + 1) * 512);
            const float4* b4 = (const float4*)bas;
            float s = 0.f;
            for (int q = 0; q < 128; ++q) {
                float4 a = b4[q], b = w4[q];
                s += a.x * b.x + a.y * b.y + a.z * b.z + a.w * b.w;
            }
            ws[OFF_GI + (jj * 32 + e) * 208 + c] = s;
        }
    } else if (blk == 64) {
        // Gram M[m][mm]
        __shared__ float basw[32 * 512];
        for (int i = tid; i < 32 * 512; i += 256) {
            int m = i >> 9, v = i & 511;
            basw[i] = (m == 0) ? 1.0f : ((m == 1) ? siv[v] : syms[(m - 2) * 512 + v]);
        }
        __syncthreads();
        for (int p = tid; p < 1024; p += 256) {
            int m = p >> 5, mm = p & 31;
            const float4* a4 = (const float4*)(basw + m * 512);
            const float4* b4 = (const float4*)(basw + mm * 512);
            float s = 0.f;
            for (int q = 0; q < 128; ++q) {
                float4 a = a4[q], b = b4[q];
                s += a.x * b.x + a.y * b.y + a.z * b.z + a.w * b.w;
            }
            ws[OFF_M + p] = s;
        }
    } else if (blk == 65) {
        // folded NAND coefs: A=(2*sig-1)/||w||, B=1-sig   for (r, j)
        for (int idx = tid; idx < 624; idx += 256) {
            int r = idx / 3, j = idx % 3;
            const float4* w4 = (const float4*)(w_row(r, pw, pow_, pfw, cw) + j * 512);
            float s = 0.f;
            for (int q = 0; q < 128; ++q) {
                float4 b = w4[q];
                s += b.x * b.x + b.y * b.y + b.z * b.z + b.w * b.w;
            }
            float nrm = fmaxf(sqrtf(s), 1e-8f);
            float nwv = nw_row(r, pn, pon, pfn, cn)[j];
            float sig = 1.f / (1.f + expf(-nwv));
            ws[OFF_A + idx]  = (2.f * sig - 1.f) / nrm;
            ws[OFF_Bc + idx] = 1.f - sig;
        }
    } else {
        // gather w j=0 slice as split-f16 hi/lo: Wh/Wl [208][512] halves — 16 blocks
        int part = blk - 66;
        _Float16* whp = (_Float16*)(ws + OFF_W0);
        _Float16* wlp = whp + 208 * 512;
        for (int i = tid; i < 6656; i += 256) {
            int flat = part * 6656 + i;
            int c = flat >> 9, v = flat & 511;
            float wv = w_row(c, pw, pow_, pfw, cw)[v];
            _Float16 h = (_Float16)wv;
            whp[flat] = h;
            wlp[flat] = (_Float16)(wv - (float)h);
        }
    }
}

// ---------------- kernel A: barrier-free split-f16 MFMA GEMM ----------------
// Block = 64 rows x 208 cols. Each wave computes all 4 row-frags x its col-tiles
// ({4,3,3,3} split). A-frags loaded directly from global x in MFMA layout
// (lane l: row m*16+(l&15), k-slice (l>>4)*8 -> one 32B contiguous load).
// Register double-buffer over kt; row norms in-register; NO LDS, NO barriers.
__global__ __launch_bounds__(256) void kA(const float* __restrict__ x, float* __restrict__ ws) {
    const int tid = threadIdx.x;
    const int wid = tid >> 6, l = tid & 63;
    const int lr = l & 15, lk = l >> 4;
    const size_t bt0 = (size_t)blockIdx.x * 64;

    const _Float16* whp = (const _Float16*)(ws + OFF_W0);
    const _Float16* wlp = whp + 208 * 512;

    const int t0 = (wid == 0) ? 0 : (1 + 3 * wid);   // 0,4,7,10
    const int nt = (wid == 0) ? 4 : 3;

    f32x4 acc[4][4];
#pragma unroll
    for (int m = 0; m < 4; ++m)
#pragma unroll
        for (int tt = 0; tt < 4; ++tt)
            acc[m][tt] = (f32x4){0.f, 0.f, 0.f, 0.f};

    float sq[4] = {0.f, 0.f, 0.f, 0.f};
    const float* xf = x + (bt0 + lr) * 512 + lk * 8;   // + m*16*512 + kt*32

    float4 cur[4][2], nxt[4][2];
#pragma unroll
    for (int m = 0; m < 4; ++m) {
        cur[m][0] = *(const float4*)(xf + m * 16 * 512);
        cur[m][1] = *(const float4*)(xf + m * 16 * 512 + 4);
    }

    for (int kt = 0; kt < 16; ++kt) {
        // prefetch next kt x (hides under this kt's MFMAs; no barriers to block it)
        if (kt < 15) {
#pragma unroll
            for (int m = 0; m < 4; ++m) {
                nxt[m][0] = *(const float4*)(xf + m * 16 * 512 + (kt + 1) * 32);
                nxt[m][1] = *(const float4*)(xf + m * 16 * 512 + (kt + 1) * 32 + 4);
            }
        }
        // convert cur -> split-f16 frags + row-norm partial
        half8 ah[4], al[4];
#pragma unroll
        for (int m = 0; m < 4; ++m) {
            float v[8];
            *(float4*)v       = cur[m][0];
            *(float4*)(v + 4) = cur[m][1];
            half8 hh, hl;
#pragma unroll
            for (int j = 0; j < 8; ++j) {
                sq[m] += v[j] * v[j];
                _Float16 h = (_Float16)v[j];
                hh[j] = h;
                hl[j] = (_Float16)(v[j] - (float)h);
            }
            ah[m] = hh; al[m] = hl;
        }
        // B loads (L2-resident) + MFMAs
        const int kof = kt * 32 + lk * 8;
#pragma unroll
        for (int tt = 0; tt < 4; ++tt) {
            if (tt < nt) {
                const int c = (t0 + tt) * 16 + lr;
                half8 bh = *(const half8*)(whp + c * 512 + kof);
                half8 bl = *(const half8*)(wlp + c * 512 + kof);
#pragma unroll
                for (int m = 0; m < 4; ++m) {
                    acc[m][tt] = __builtin_amdgcn_mfma_f32_16x16x32_f16(ah[m], bh, acc[m][tt], 0, 0, 0);
                    acc[m][tt] = __builtin_amdgcn_mfma_f32_16x16x32_f16(ah[m], bl, acc[m][tt], 0, 0, 0);
                    acc[m][tt] = __builtin_amdgcn_mfma_f32_16x16x32_f16(al[m], bh, acc[m][tt], 0, 0, 0);
                }
            }
        }
        if (kt < 15) {
#pragma unroll
            for (int m = 0; m < 4; ++m) { cur[m][0] = nxt[m][0]; cur[m][1] = nxt[m][1]; }
        }
    }

    // in-register row norms: lanes {lr, lr+16, lr+32, lr+48} hold k-partials of
    // row m*16+lr -> combine with xor16 (DS swizzle, one-time) + xor32 (VALU).
    float ivx[4];
#pragma unroll
    for (int m = 0; m < 4; ++m) {
        float rs = sq[m];
        rs += swz16(rs);
        rs += xor32(rs);
        ivx[m] = __frsqrt_rn(fmaxf(rs, 1e-16f));   // == 1/max(sqrt(rs),1e-8)
    }

    // epilogue: interp0 = A0*|dot|*invx + B0.  D frag: col=lane&15, row=(lane>>4)*4+reg
#pragma unroll
    for (int tt = 0; tt < 4; ++tt) {
        if (tt < nt) {
            const int c = (t0 + tt) * 16 + lr;
            const float A0 = ws[OFF_A + c * 3];
            const float B0 = ws[OFF_Bc + c * 3];
#pragma unroll
            for (int m = 0; m < 4; ++m) {
                const int rbase = m * 16 + lk * 4;
#pragma unroll
                for (int j = 0; j < 4; ++j) {
                    const float ix = __shfl(ivx[m], lk * 4 + j);   // row's norm lives in lane (row&15)
                    ws[OFF_I0 + (bt0 + rbase + j) * 208 + c] = A0 * fabsf(acc[m][tt][j]) * ix + B0;
                }
            }
        }
    }
}

// ---------------- kernel C: serial scan, 1 barrier/step, VALU cross-lane ----------------
// Every thread owns row r = (wid==3)? 144+l : tid  (tid 144..191 = valid junk).
// pk gathered via in-wave v_readlane; pk0/pk1 per-lane components + pkOther via
// v_permlane32_swap (VALU); norm 32-sum via sum16 DPP + 2 readlanes.
__global__ __attribute__((amdgpu_flat_work_group_size(256, 256), amdgpu_waves_per_eu(1, 1)))
void kC(float* __restrict__ ws, const float* __restrict__ sharp) {
    __shared__ float nndL[2][144];
    const int b = blockIdx.x, tid = threadIdx.x;
    const int wid = tid >> 6, l = tid & 63;
    const int k = l >> 5, m = l & 31;
    const int isW3 = (wid == 3);
    const int isRow = (tid < 144);
    const int r = isW3 ? (144 + l) : tid;          // owned NAND row

    const float* GI = ws + OFF_GI;
    float G[64];
#pragma unroll
    for (int i = 0; i < 32; ++i) {
        G[i]      = GI[i * 208 + r];
        G[32 + i] = GI[(32 + i) * 208 + r];
    }
    const float A1 = ws[OFF_A + r * 3 + 1],  A2 = ws[OFF_A + r * 3 + 2];
    const float B1 = ws[OFF_Bc + r * 3 + 1], B2 = ws[OFF_Bc + r * 3 + 2];
    float Mrow[32];
#pragma unroll
    for (int q = 0; q < 8; ++q) {
        float4 mr = *(const float4*)(ws + OFF_M + m * 32 + 4 * q);
        Mrow[4*q] = mr.x; Mrow[4*q+1] = mr.y; Mrow[4*q+2] = mr.z; Mrow[4*q+3] = mr.w;
    }
    const float sh = sharp[k];

    // replicated stack state
    float st[4], p[4];
#pragma unroll
    for (int d = 0; d < 4; ++d) {
        st[d] = (d == 1) ? ((m == 1) ? 1.f : 0.f) : ((m == 0) ? ZOFF : 0.f);
        p[d] = (d == 1) ? 1.f : 0.f;
    }
    float pk = st[0] * p[0] + st[1] * p[1] + st[2] * p[2] + st[3] * p[3];
    float pkOther = xor32(pk);

    const float* i0base = ws + OFF_I0 + (size_t)b * SS * 208;
    const int ioff = isW3 ? 0 : 1;                 // rows consume i0(t+1), w3 i0(t)
    float i0pro = i0base[r];                       // i0(0) for prologue
    float i0use = i0base[(size_t)ioff * 208 + r];  // rows: i0(1), w3: i0(0)

    // CA: pp = own pkp; pk0v/pk1v from permlane; readlane gather for dots/gram
    auto CA = [&](float pp, float pk0v, float pk1v, float iv) -> float {
        float gq0a = 0.f, gq0b = 0.f, gq1a = 0.f, gq1b = 0.f;
        float d1a = 0.f, d1b = 0.f, d2a = 0.f, d2b = 0.f;
#pragma unroll
        for (int mm = 0; mm < 32; ++mm) {
            float v0 = rlane(pp, mm);        // pk0[mm]
            float v1 = rlane(pp, 32 + mm);   // pk1[mm]
            if (mm & 1) {
                gq0b += Mrow[mm] * v0;  gq1b += Mrow[mm] * v1;
                d1b  += G[mm] * v0;     d2b  += G[32 + mm] * v1;
            } else {
                gq0a += Mrow[mm] * v0;  gq1a += Mrow[mm] * v1;
                d1a  += G[mm] * v0;     d2a  += G[32 + mm] * v1;
            }
        }
        // per-lane quadratic-form contributions; 32-sum = sum16 (DPP) + 2 readlanes
        float pm0 = pk0v * (gq0a + gq0b);
        float pm1 = pk1v * (gq1a + gq1b);
        float s0 = sum16(pm0);
        float s1 = sum16(pm1);
        float q0 = rlane(s0, 0) + rlane(s0, 16);
        float q1 = rlane(s1, 0) + rlane(s1, 16);
        float iq0 = __frsqrt_rn(fmaxf(q0, 1e-16f));
        float iq1 = __frsqrt_rn(fmaxf(q1, 1e-16f));
        float dd1 = d1a + d1b, dd2 = d2a + d2b;
        return iv * (A1 * fabsf(dd1) * iq0 + B1) * (A2 * fabsf(dd2) * iq1 + B2);
    };

    // ---- prologue: nnd(0) -> nndL[0] ----
    {
        float lo0, hi0;
        swap32(pk, lo0, hi0);
        float nv0 = CA(pk, lo0, hi0, i0pro);
        if (isRow) nndL[0][tid] = nv0;
    }
    __syncthreads();

    for (int t = 0; t < SS; ++t) {
        // early prefetch of next i0 (global latency hides under this step)
        int nidx = t + 1 + ioff; if (nidx > SS - 1) nidx = SS - 1;
        float i0nxt = i0base[(size_t)nidx * 208 + r];

        const float* nb = nndL[t & 1];
        // ---- gates + push_val + state update (replicated in all waves) ----
        float4 gp4 = *(const float4*)(nb + 4 * k);
        float4 gq4 = *(const float4*)(nb + 8 + 4 * k);
        float prp0 = 1.f / (1.f + __expf((fmaxf(gp4.z, gp4.w) - fmaxf(gp4.x, gp4.y)) * sh));
        float prq0 = 1.f / (1.f + __expf((fmaxf(gq4.z, gq4.w) - fmaxf(gq4.x, gq4.y)) * sh));
        float prp1 = 1.f - prp0, prq1 = 1.f - prq0;
        float prx = 0.f, pry = 0.f;
        if (m >= 2) {
            float2 pr2 = *(const float2*)(nb + 16 + 64 * k + 2 * m - 4);
            prx = pr2.x; pry = pr2.y;
        }
        float4 t30 = *(const float4*)(nb + 16 + 64 * k + 60);
        float pk0m = k ? pkOther : pk;
        float pk1m = k ? pk : pkOther;
        float pvc = prx + pry + (t30.x + t30.y) * pk0m + (t30.z + t30.w) * pk1m;

        float zc = (m == 0) ? ZOFF : 0.f;
        float s1v[4], p1[4];
#pragma unroll
        for (int d = 0; d < 4; ++d) {
            float ps = st[d] * (1.f - p[d]) + zc * p[d];
            s1v[d] = ps * prp0 + st[d] * prp1;
            p1[d] = p[(d + 1) & 3] * prp0 + p[d] * prp1;
        }
#pragma unroll
        for (int d = 0; d < 4; ++d) {
            float pu = p1[(d + 3) & 3];
            float su = s1v[d] * (1.f - pu) + pvc * pu;
            st[d] = su * prq0 + s1v[d] * prq1;
            p[d] = pu * prq0 + p1[d] * prq1;
        }
        float pkp = st[0] * p[0] + st[1] * p[1] + st[2] * p[2] + st[3] * p[3];
        // pk0/pk1 components + cross value via permlane (VALU, no DS)
        float pk0v, pk1v;
        swap32(pkp, pk0v, pk1v);
        float pkpOth = k ? pk0v : pk1v;

        // ---- fused gram + dots + nnd ----
        float nv = CA(pkp, pk0v, pk1v, i0use);
        if (isRow) nndL[(t + 1) & 1][tid] = nv;
        if (isW3) {
            // out coords via lane ops over per-lane nnd2 (calc row 144+lane)
            float s60 = rlane(nv, 60), s61 = rlane(nv, 61);
            float s62 = rlane(nv, 62), s63 = rlane(nv, 63);
            int src = (m >= 2) ? (2 * m - 4) : 0;
            float cx = __shfl(nv, src);
            float cy = __shfl(nv, src + 1);
            if (m < 2) { cx = 0.f; cy = 0.f; }
            if (l < 32) {
                float oc = cx + cy + (s60 + s61) * pkp + (s62 + s63) * pkpOth;
                ws[OFF_OC + ((size_t)b * SS + t) * 32 + m] = oc;
            }
        }
        __syncthreads();   // nndL(t+1) visible for next step
        pk = pkp;
        pkOther = pkpOth;
        i0use = i0nxt;
    }
}

// ---------------- kernel D: expand coords -> 512-dim output (barrier-free) ----------------
__global__ __launch_bounds__(256) void kD(const float* __restrict__ ws, const float* __restrict__ syms,
                                          const float* __restrict__ siv, float* __restrict__ out) {
    int t = threadIdx.x;
    int rg = t >> 6;
    int vc = (t & 63) * 8;
    size_t r0 = (size_t)blockIdx.x * 16 + rg * 4;
    const float* oc = ws + OFF_OC;
    float acc[4][8];
    float4 sv0 = *(const float4*)(siv + vc);
    float4 sv1 = *(const float4*)(siv + vc + 4);
#pragma unroll
    for (int rr = 0; rr < 4; ++rr) {
        float c0 = oc[(r0 + rr) * 32 + 0];
        float c1 = oc[(r0 + rr) * 32 + 1];
        acc[rr][0] = c0 + c1 * sv0.x; acc[rr][1] = c0 + c1 * sv0.y;
        acc[rr][2] = c0 + c1 * sv0.z; acc[rr][3] = c0 + c1 * sv0.w;
        acc[rr][4] = c0 + c1 * sv1.x; acc[rr][5] = c0 + c1 * sv1.y;
        acc[rr][6] = c0 + c1 * sv1.z; acc[rr][7] = c0 + c1 * sv1.w;
    }
    for (int mm = 0; mm < 30; ++mm) {
        float4 b0 = *(const float4*)(syms + mm * 512 + vc);
        float4 b1 = *(const float4*)(syms + mm * 512 + vc + 4);
#pragma unroll
        for (int rr = 0; rr < 4; ++rr) {
            float c = oc[(r0 + rr) * 32 + 2 + mm];
            acc[rr][0] += c * b0.x; acc[rr][1] += c * b0.y;
            acc[rr][2] += c * b0.z; acc[rr][3] += c * b0.w;
            acc[rr][4] += c * b1.x; acc[rr][5] += c * b1.y;
            acc[rr][6] += c * b1.z; acc[rr][7] += c * b1.w;
        }
    }
#pragma unroll
    for (int rr = 0; rr < 4; ++rr) {
        float* o = out + (r0 + rr) * 512 + vc;
        *(float4*)o       = make_float4(acc[rr][0], acc[rr][1], acc[rr][2], acc[rr][3]);
        *(float4*)(o + 4) = make_float4(acc[rr][4], acc[rr][5], acc[rr][6], acc[rr][7]);
    }
}

extern "C" void kernel_launch(void* const* d_in, const int* in_sizes, int n_in,
                              void* d_out, int out_size, void* d_ws, size_t ws_size,
                              hipStream_t stream) {
    const float* x    = (const float*)d_in[0];
    const float* syms = (const float*)d_in[1];
    const float* siv  = (const float*)d_in[2];
    const float* shp  = (const float*)d_in[3];
    const float* pw   = (const float*)d_in[4];
    const float* pn   = (const float*)d_in[5];
    const float* pow_ = (const float*)d_in[6];
    const float* pon  = (const float*)d_in[7];
    const float* pfw  = (const float*)d_in[8];
    const float* pfn  = (const float*)d_in[9];
    const float* cw   = (const float*)d_in[10];
    const float* cn   = (const float*)d_in[11];
    float* ws  = (float*)d_ws;
    float* out = (float*)d_out;

    hipLaunchKernelGGL(kB, dim3(82),   dim3(256), 0, stream,
                       syms, siv, pw, pn, pow_, pon, pfw, pfn, cw, cn, ws);
    hipLaunchKernelGGL(kA, dim3(512),  dim3(256), 0, stream, x, ws);
    hipLaunchKernelGGL(kC, dim3(256),  dim3(256), 0, stream, ws, shp);
    hipLaunchKernelGGL(kD, dim3(2048), dim3(256), 0, stream, ws, syms, siv, out);
}

// Round 10
// 375.792 us; speedup vs baseline: 1.0618x; 1.0618x over previous
//
#include <hip/hip_runtime.h>
#include <math.h>

// Cyborg stack machine: B=256, S=128, V=512, H=30, N_STACKS=2, R=2, DEPTH=4
// All stack/peek/output vectors live in span{ones, init_vec, syms0..29} (32-dim).
// kA (R14): R11 split-f16 MFMA GEMM, but 2 col-blocks per row-block (grid 1024,
//   4 blocks/CU instead of 2) — barrier stalls overlap across blocks.
// kC (R14): R11 structure (readlane gather, 1 barrier/step) + packed f32x2 FMA
//   chains: tables interleaved {G, Mrow} -> v_pk_fma_f32 halves the dot+gram
//   instruction count. Accumulation pairing identical to R11 (bit-compatible).

#define SS 128
#define VV 512
#define NROWS 208      // 8 pop + 8 pushop + 128 pushfn + 64 calc
#define ZOFF 1e-6f

// ws layout (float offsets)
#define OFF_I0   0                          // interp0: 32768*208
#define OFF_OC   (32768*208)                // out coords: 32768*32
#define OFF_GI   (OFF_OC + 32768*32)        // G[2][32][208]  (stack, basis, row)
#define OFF_M    (OFF_GI + 2*32*208)        // Gram 32*32
#define OFF_A    (OFF_M + 1024)             // A coef 208*3
#define OFF_Bc   (OFF_A + 624)              // B coef 208*3
#define OFF_W0   (OFF_Bc + 624)             // Wh/Wl f16: 2 x [208][512] halves

typedef _Float16 half8 __attribute__((ext_vector_type(8)));
typedef float f32x4 __attribute__((ext_vector_type(4)));
typedef float f32x2 __attribute__((ext_vector_type(2)));

__device__ __forceinline__ float rlane(float v, int lane) {
    return __int_as_float(__builtin_amdgcn_readlane(__float_as_int(v), lane));
}
template <int CTRL>
__device__ __forceinline__ float dpp_add(float x) {
    int y = __builtin_amdgcn_update_dpp(0, __float_as_int(x), CTRL, 0xF, 0xF, true);
    return x + __int_as_float(y);
}
// full 16-lane row sum, result in all lanes of the row (pure VALU)
__device__ __forceinline__ float sum16(float x) {
    x = dpp_add<0xB1>(x);    // quad_perm [1,0,3,2]  (xor 1)
    x = dpp_add<0x4E>(x);    // quad_perm [2,3,0,1]  (xor 2)
    x = dpp_add<0x124>(x);   // row_ror:4
    x = dpp_add<0x128>(x);   // row_ror:8
    return x;
}
__device__ __forceinline__ float swz16(float x) {   // lane ^ 16 within 32-group
    return __int_as_float(__builtin_amdgcn_ds_swizzle(__float_as_int(x), 0x401F));
}

__device__ __forceinline__ const float* w_row(int r, const float* pw, const float* pow_,
                                              const float* pfw, const float* cw) {
    if (r < 8)   return pw   + r * 1536;
    if (r < 16)  return pow_ + (r - 8) * 1536;
    if (r < 144) return pfw  + (r - 16) * 1536;
    return cw + (r - 144) * 1536;
}
__device__ __forceinline__ const float* nw_row(int r, const float* pn, const float* pon,
                                               const float* pfn, const float* cn) {
    if (r < 8)   return pn   + r * 3;
    if (r < 16)  return pon  + (r - 8) * 3;
    if (r < 144) return pfn  + (r - 16) * 3;
    return cn + (r - 144) * 3;
}

// ---------------- kernel B: precompute tables ----------------
__global__ void kB(const float* __restrict__ syms, const float* __restrict__ siv,
                   const float* __restrict__ pw, const float* __restrict__ pn,
                   const float* __restrict__ pow_, const float* __restrict__ pon,
                   const float* __restrict__ pfw, const float* __restrict__ pfn,
                   const float* __restrict__ cw, const float* __restrict__ cn,
                   float* __restrict__ ws) {
    int blk = blockIdx.x, tid = threadIdx.x;
    if (blk < 64) {
        // G[jj][e][c] = basis_e . w_row(c)[(jj+1)*512 ..)
        int jj = blk >> 5, e = blk & 31;
        __shared__ float bas[512];
        for (int i = tid; i < 512; i += 256)
            bas[i] = (e == 0) ? 1.0f : ((e == 1) ? siv[i] : syms[(e - 2) * 512 + i]);
        __syncthreads();
        if (tid < NROWS) {
            int c = tid;
            const float4* w4 = (const float4*)(w_row(c, pw, pow_, pfw, cw) + (jj + 1) * 512);
            const float4* b4 = (const float4*)bas;
            float s = 0.f;
            for (int q = 0; q < 128; ++q) {
                float4 a = b4[q], b = w4[q];
                s += a.x * b.x + a.y * b.y + a.z * b.z + a.w * b.w;
            }
            ws[OFF_GI + (jj * 32 + e) * 208 + c] = s;
        }
    } else if (blk == 64) {
        // Gram M[m][mm]
        __shared__ float basw[32 * 512];
        for (int i = tid; i < 32 * 512; i += 256) {
            int m = i >> 9, v = i & 511;
            basw[i] = (m == 0) ? 1.0f : ((m == 1) ? siv[v] : syms[(m - 2) * 512 + v]);
        }
        __syncthreads();
        for (int p = tid; p < 1024; p += 256) {
            int m = p >> 5, mm = p & 31;
            const float4* a4 = (const float4*)(basw + m * 512);
            const float4* b4 = (const float4*)(basw + mm * 512);
            float s = 0.f;
            for (int q = 0; q < 128; ++q) {
                float4 a = a4[q], b = b4[q];
                s += a.x * b.x + a.y * b.y + a.z * b.z + a.w * b.w;
            }
            ws[OFF_M + p] = s;
        }
    } else if (blk == 65) {
        // folded NAND coefs: A=(2*sig-1)/||w||, B=1-sig   for (r, j)
        for (int idx = tid; idx < 624; idx += 256) {
            int r = idx / 3, j = idx % 3;
            const float4* w4 = (const float4*)(w_row(r, pw, pow_, pfw, cw) + j * 512);
            float s = 0.f;
            for (int q = 0; q < 128; ++q) {
                float4 b = w4[q];
                s += b.x * b.x + b.y * b.y + b.z * b.z + b.w * b.w;
            }
            float nrm = fmaxf(sqrtf(s), 1e-8f);
            float nwv = nw_row(r, pn, pon, pfn, cn)[j];
            float sig = 1.f / (1.f + expf(-nwv));
            ws[OFF_A + idx]  = (2.f * sig - 1.f) / nrm;
            ws[OFF_Bc + idx] = 1.f - sig;
        }
    } else {
        // gather w j=0 slice as split-f16 hi/lo: Wh/Wl [208][512] halves — 16 blocks
        int part = blk - 66;
        _Float16* whp = (_Float16*)(ws + OFF_W0);
        _Float16* wlp = whp + 208 * 512;
        for (int i = tid; i < 6656; i += 256) {
            int flat = part * 6656 + i;
            int c = flat >> 9, v = flat & 511;
            float wv = w_row(c, pw, pow_, pfw, cw)[v];
            _Float16 h = (_Float16)wv;
            whp[flat] = h;
            wlp[flat] = (_Float16)(wv - (float)h);
        }
    }
}

// ---------------- kernel A: interp0 via split-f16 MFMA GEMM ----------------
// grid = 1024: bid>>1 = row-block (64 rows), bid&1 = col-half. Global wave id
// gw = (bid&1)*4+wid in [0,8) takes tiles {2,2,2,2,2,1,1,1} of the 13 col-tiles.
// 4 blocks/CU (vs 2) -> cross-block overlap of the per-kt barrier stalls.
__global__ __launch_bounds__(256) void kA(const float* __restrict__ x, float* __restrict__ ws) {
    __shared__ half8 AH[2][256];   // [buf][mfrag*64 + fraglane]
    __shared__ half8 AL[2][256];
    __shared__ float red[256];
    __shared__ float invx[64];
    const int tid = threadIdx.x;
    const int wid = tid >> 6, l = tid & 63;
    const int bid = blockIdx.x;
    const size_t bt0 = (size_t)(bid >> 1) * 64;

    const int sr = tid >> 2, ss = tid & 3;
    const float* xp = x + (bt0 + sr) * 512 + ss * 8;
    const int wpos = (sr >> 4) * 64 + (sr & 15) + (ss << 4);   // frag slot

    const _Float16* whp = (const _Float16*)(ws + OFF_W0);
    const _Float16* wlp = whp + 208 * 512;

    const int gw = ((bid & 1) << 2) | wid;           // 0..7
    const int nt = (gw < 5) ? 2 : 1;
    const int t0 = (gw < 5) ? (2 * gw) : (5 + gw);   // tiles 0..9 / 10,11,12

    f32x4 acc[4][2];
#pragma unroll
    for (int m = 0; m < 4; ++m)
#pragma unroll
        for (int tt = 0; tt < 2; ++tt)
            acc[m][tt] = (f32x4){0.f, 0.f, 0.f, 0.f};

    float sumsq = 0.f;

    // prologue stage of kt=0
    {
        float v[8];
        *(float4*)v       = *(const float4*)(xp);
        *(float4*)(v + 4) = *(const float4*)(xp + 4);
        half8 hh, hl;
#pragma unroll
        for (int j = 0; j < 8; ++j) {
            sumsq += v[j] * v[j];
            _Float16 h = (_Float16)v[j];
            hh[j] = h;
            hl[j] = (_Float16)(v[j] - (float)h);
        }
        AH[0][wpos] = hh;
        AL[0][wpos] = hl;
    }
    __syncthreads();

    for (int kt = 0; kt < 16; ++kt) {
        const int buf = kt & 1;
        // 1) A-fragment LDS reads first
        half8 ahm[4], alm[4];
#pragma unroll
        for (int m = 0; m < 4; ++m) {
            ahm[m] = AH[buf][m * 64 + l];
            alm[m] = AL[buf][m * 64 + l];
        }
        // 2) issue next-kt x loads EARLY (latency hides under MFMAs)
        float4 xv0, xv1;
        if (kt < 15) {
            xv0 = *(const float4*)(xp + (kt + 1) * 32);
            xv1 = *(const float4*)(xp + (kt + 1) * 32 + 4);
        }
        // 3) B loads + MFMAs
        const int kof = kt * 32 + (l >> 4) * 8;
#pragma unroll
        for (int tt = 0; tt < 2; ++tt) {
            if (tt < nt) {
                const int c = (t0 + tt) * 16 + (l & 15);
                half8 bh = *(const half8*)(whp + c * 512 + kof);
                half8 bl = *(const half8*)(wlp + c * 512 + kof);
#pragma unroll
                for (int m = 0; m < 4; ++m) {
                    acc[m][tt] = __builtin_amdgcn_mfma_f32_16x16x32_f16(ahm[m], bh, acc[m][tt], 0, 0, 0);
                    acc[m][tt] = __builtin_amdgcn_mfma_f32_16x16x32_f16(ahm[m], bl, acc[m][tt], 0, 0, 0);
                    acc[m][tt] = __builtin_amdgcn_mfma_f32_16x16x32_f16(alm[m], bh, acc[m][tt], 0, 0, 0);
                }
            }
        }
        // 4) write-late: convert + LDS store of next tile after MFMAs issued
        if (kt < 15) {
            float v[8];
            *(float4*)v = xv0; *(float4*)(v + 4) = xv1;
            half8 hh, hl;
#pragma unroll
            for (int j = 0; j < 8; ++j) {
                sumsq += v[j] * v[j];
                _Float16 h = (_Float16)v[j];
                hh[j] = h;
                hl[j] = (_Float16)(v[j] - (float)h);
            }
            AH[buf ^ 1][wpos] = hh;
            AL[buf ^ 1][wpos] = hl;
        }
        __syncthreads();
    }

    red[tid] = sumsq;
    __syncthreads();
    if (tid < 64) {
        float s = red[tid * 4] + red[tid * 4 + 1] + red[tid * 4 + 2] + red[tid * 4 + 3];
        invx[tid] = 1.f / fmaxf(sqrtf(s), 1e-8f);
    }
    __syncthreads();

    // epilogue: interp0 = A0*|dot|*invx + B0.  D frag: col=lane&15, row=(lane>>4)*4+reg
#pragma unroll
    for (int tt = 0; tt < 2; ++tt) {
        if (tt < nt) {
            const int c = (t0 + tt) * 16 + (l & 15);
            const float A0 = ws[OFF_A + c * 3];
            const float B0 = ws[OFF_Bc + c * 3];
#pragma unroll
            for (int m = 0; m < 4; ++m) {
                const int rbase = m * 16 + (l >> 4) * 4;
#pragma unroll
                for (int j = 0; j < 4; ++j) {
                    const float ix = invx[rbase + j];
                    ws[OFF_I0 + (bt0 + rbase + j) * 208 + c] = A0 * fabsf(acc[m][tt][j]) * ix + B0;
                }
            }
        }
    }
}

// ---------------- kernel C: serial scan, 1 barrier/step, packed-FMA readlane gather ----------------
// Every thread owns row r = (wid==3)? 144+l : tid  (tid 144..191 = valid junk).
// Tables interleaved f32x2 {G, Mrow} -> v_pk_fma_f32 halves dot+gram inst count.
// Per step: gates(nndL[t&1]) -> update -> pkp -> readlane packed dots+gram ->
//   DPP sum16 + swz16 -> iq -> nnd -> nndL[(t+1)&1] / oc -> ONE barrier.
__global__ __attribute__((amdgpu_flat_work_group_size(256, 256), amdgpu_waves_per_eu(1, 1)))
void kC(float* __restrict__ ws, const float* __restrict__ sharp) {
    __shared__ float nndL[2][144];
    const int b = blockIdx.x, tid = threadIdx.x;
    const int wid = tid >> 6, l = tid & 63;
    const int k = l >> 5, m = l & 31;
    const int isW3 = (wid == 3);
    const int isRow = (tid < 144);
    const int r = isW3 ? (144 + l) : tid;          // owned NAND row

    const float* GI = ws + OFF_GI;
    // interleaved tables: GM1[i] = {G1[i], M[m][i]}, GM2[i] = {G2[i], M[m][i]}
    f32x2 GM1[32], GM2[32];
#pragma unroll
    for (int i = 0; i < 32; ++i) {
        float mv = ws[OFF_M + m * 32 + i];
        GM1[i] = (f32x2){GI[i * 208 + r], mv};
        GM2[i] = (f32x2){GI[(32 + i) * 208 + r], mv};
    }
    const float A1 = ws[OFF_A + r * 3 + 1],  A2 = ws[OFF_A + r * 3 + 2];
    const float B1 = ws[OFF_Bc + r * 3 + 1], B2 = ws[OFF_Bc + r * 3 + 2];
    const float sh = sharp[k];

    // replicated stack state
    float st[4], p[4];
#pragma unroll
    for (int d = 0; d < 4; ++d) {
        st[d] = (d == 1) ? ((m == 1) ? 1.f : 0.f) : ((m == 0) ? ZOFF : 0.f);
        p[d] = (d == 1) ? 1.f : 0.f;
    }
    float pk = st[0] * p[0] + st[1] * p[1] + st[2] * p[2] + st[3] * p[3];
    float pkOther = __shfl_xor(pk, 32);

    const float* i0base = ws + OFF_I0 + (size_t)b * SS * 208;
    const int ioff = isW3 ? 0 : 1;                 // rows consume i0(t+1), w3 i0(t)
    float i0pro = i0base[r];                       // i0(0) for prologue
    float i0use = i0base[(size_t)ioff * 208 + r];  // rows: i0(1), w3: i0(0)

    // CA: readlane gather; packed f32x2 FMA chains {dot, gram} sharing v0/v1
    auto CA = [&](float pp, float po, float iv) -> float {
        f32x2 a1 = (f32x2){0.f, 0.f}, b1 = (f32x2){0.f, 0.f};
        f32x2 a2 = (f32x2){0.f, 0.f}, b2 = (f32x2){0.f, 0.f};
#pragma unroll
        for (int mm = 0; mm < 32; ++mm) {
            float v0 = rlane(pp, mm);        // pk0[mm]
            float v1 = rlane(pp, 32 + mm);   // pk1[mm]
            if (mm & 1) { b1 += GM1[mm] * v0;  b2 += GM2[mm] * v1; }
            else        { a1 += GM1[mm] * v0;  a2 += GM2[mm] * v1; }
        }
        float dd1 = a1.x + b1.x, gq0 = a1.y + b1.y;
        float dd2 = a2.x + b2.x, gq1 = a2.y + b2.y;
        // both quadratic forms per lane: own pk0/pk1 component times (M.pk)
        float pm0 = (k ? po : pp) * gq0;
        float pm1 = (k ? pp : po) * gq1;
        float q0 = sum16(pm0); q0 += swz16(q0);
        float q1 = sum16(pm1); q1 += swz16(q1);
        float iq0 = __frsqrt_rn(fmaxf(q0, 1e-16f));
        float iq1 = __frsqrt_rn(fmaxf(q1, 1e-16f));
        return iv * (A1 * fabsf(dd1) * iq0 + B1) * (A2 * fabsf(dd2) * iq1 + B2);
    };

    // ---- prologue: nnd(0) -> nndL[0] ----
    {
        float nv0 = CA(pk, pkOther, i0pro);
        if (isRow) nndL[0][tid] = nv0;
    }
    __syncthreads();

    for (int t = 0; t < SS; ++t) {
        // early prefetch of next i0 (global latency hides under this step)
        int nidx = t + 1 + ioff; if (nidx > SS - 1) nidx = SS - 1;
        float i0nxt = i0base[(size_t)nidx * 208 + r];

        const float* nb = nndL[t & 1];
        // ---- gates + push_val + state update (replicated in all waves) ----
        float4 gp4 = *(const float4*)(nb + 4 * k);
        float4 gq4 = *(const float4*)(nb + 8 + 4 * k);
        float prp0 = 1.f / (1.f + __expf((fmaxf(gp4.z, gp4.w) - fmaxf(gp4.x, gp4.y)) * sh));
        float prq0 = 1.f / (1.f + __expf((fmaxf(gq4.z, gq4.w) - fmaxf(gq4.x, gq4.y)) * sh));
        float prp1 = 1.f - prp0, prq1 = 1.f - prq0;
        float prx = 0.f, pry = 0.f;
        if (m >= 2) {
            float2 pr2 = *(const float2*)(nb + 16 + 64 * k + 2 * m - 4);
            prx = pr2.x; pry = pr2.y;
        }
        float4 t30 = *(const float4*)(nb + 16 + 64 * k + 60);
        float pk0m = k ? pkOther : pk;
        float pk1m = k ? pk : pkOther;
        float pvc = prx + pry + (t30.x + t30.y) * pk0m + (t30.z + t30.w) * pk1m;

        float zc = (m == 0) ? ZOFF : 0.f;
        float s1v[4], p1[4];
#pragma unroll
        for (int d = 0; d < 4; ++d) {
            float ps = st[d] * (1.f - p[d]) + zc * p[d];
            s1v[d] = ps * prp0 + st[d] * prp1;
            p1[d] = p[(d + 1) & 3] * prp0 + p[d] * prp1;
        }
#pragma unroll
        for (int d = 0; d < 4; ++d) {
            float pu = p1[(d + 3) & 3];
            float su = s1v[d] * (1.f - pu) + pvc * pu;
            st[d] = su * prq0 + s1v[d] * prq1;
            p[d] = pu * prq0 + p1[d] * prq1;
        }
        float pkp = st[0] * p[0] + st[1] * p[1] + st[2] * p[2] + st[3] * p[3];
        float pkpOth = __shfl_xor(pkp, 32);

        // ---- fused gram + dots + nnd ----
        float nv = CA(pkp, pkpOth, i0use);
        if (isRow) nndL[(t + 1) & 1][tid] = nv;
        if (isW3) {
            // out coords via lane ops over per-lane nnd2 (calc row 144+lane)
            float s60 = rlane(nv, 60), s61 = rlane(nv, 61);
            float s62 = rlane(nv, 62), s63 = rlane(nv, 63);
            int src = (m >= 2) ? (2 * m - 4) : 0;
            float cx = __shfl(nv, src);
            float cy = __shfl(nv, src + 1);
            if (m < 2) { cx = 0.f; cy = 0.f; }
            if (l < 32) {
                float oc = cx + cy + (s60 + s61) * pkp + (s62 + s63) * pkpOth;
                ws[OFF_OC + ((size_t)b * SS + t) * 32 + m] = oc;
            }
        }
        __syncthreads();   // nndL(t+1) visible for next step
        pk = pkp;
        pkOther = pkpOth;
        i0use = i0nxt;
    }
}

// ---------------- kernel D: expand coords -> 512-dim output (barrier-free) ----------------
__global__ __launch_bounds__(256) void kD(const float* __restrict__ ws, const float* __restrict__ syms,
                                          const float* __restrict__ siv, float* __restrict__ out) {
    int t = threadIdx.x;
    int rg = t >> 6;
    int vc = (t & 63) * 8;
    size_t r0 = (size_t)blockIdx.x * 16 + rg * 4;
    const float* oc = ws + OFF_OC;
    float acc[4][8];
    float4 sv0 = *(const float4*)(siv + vc);
    float4 sv1 = *(const float4*)(siv + vc + 4);
#pragma unroll
    for (int rr = 0; rr < 4; ++rr) {
        float c0 = oc[(r0 + rr) * 32 + 0];
        float c1 = oc[(r0 + rr) * 32 + 1];
        acc[rr][0] = c0 + c1 * sv0.x; acc[rr][1] = c0 + c1 * sv0.y;
        acc[rr][2] = c0 + c1 * sv0.z; acc[rr][3] = c0 + c1 * sv0.w;
        acc[rr][4] = c0 + c1 * sv1.x; acc[rr][5] = c0 + c1 * sv1.y;
        acc[rr][6] = c0 + c1 * sv1.z; acc[rr][7] = c0 + c1 * sv1.w;
    }
    for (int mm = 0; mm < 30; ++mm) {
        float4 b0 = *(const float4*)(syms + mm * 512 + vc);
        float4 b1 = *(const float4*)(syms + mm * 512 + vc + 4);
#pragma unroll
        for (int rr = 0; rr < 4; ++rr) {
            float c = oc[(r0 + rr) * 32 + 2 + mm];
            acc[rr][0] += c * b0.x; acc[rr][1] += c * b0.y;
            acc[rr][2] += c * b0.z; acc[rr][3] += c * b0.w;
            acc[rr][4] += c * b1.x; acc[rr][5] += c * b1.y;
            acc[rr][6] += c * b1.z; acc[rr][7] += c * b1.w;
        }
    }
#pragma unroll
    for (int rr = 0; rr < 4; ++rr) {
        float* o = out + (r0 + rr) * 512 + vc;
        *(float4*)o       = make_float4(acc[rr][0], acc[rr][1], acc[rr][2], acc[rr][3]);
        *(float4*)(o + 4) = make_float4(acc[rr][4], acc[rr][5], acc[rr][6], acc[rr][7]);
    }
}

extern "C" void kernel_launch(void* const* d_in, const int* in_sizes, int n_in,
                              void* d_out, int out_size, void* d_ws, size_t ws_size,
                              hipStream_t stream) {
    const float* x    = (const float*)d_in[0];
    const float* syms = (const float*)d_in[1];
    const float* siv  = (const float*)d_in[2];
    const float* shp  = (const float*)d_in[3];
    const float* pw   = (const float*)d_in[4];
    const float* pn   = (const float*)d_in[5];
    const float* pow_ = (const float*)d_in[6];
    const float* pon  = (const float*)d_in[7];
    const float* pfw  = (const float*)d_in[8];
    const float* pfn  = (const float*)d_in[9];
    const float* cw   = (const float*)d_in[10];
    const float* cn   = (const float*)d_in[11];
    float* ws  = (float*)d_ws;
    float* out = (float*)d_out;

    hipLaunchKernelGGL(kB, dim3(82),   dim3(256), 0, stream,
                       syms, siv, pw, pn, pow_, pon, pfw, pfn, cw, cn, ws);
    hipLaunchKernelGGL(kA, dim3(1024), dim3(256), 0, stream, x, ws);
    hipLaunchKernelGGL(kC, dim3(256),  dim3(256), 0, stream, ws, shp);
    hipLaunchKernelGGL(kD, dim3(2048), dim3(256), 0, stream, ws, syms, siv, out);
}

// Round 11
// 358.577 us; speedup vs baseline: 1.1128x; 1.0480x over previous
//
#include <hip/hip_runtime.h>
#include <math.h>

// Cyborg stack machine: B=256, S=128, V=512, H=30, N_STACKS=2, R=2, DEPTH=4
// All stack/peek/output vectors live in span{ones, init_vec, syms0..29} (32-dim).
// kA (R14): split-f16 MFMA GEMM, 2 col-blocks per row-block (grid 1024).
// kC (R15): R14 scan + FUSED OUTPUT EXPANSION (kD deleted). wave3 publishes
//   oc(t) to double-buffered LDS; next step all threads expand step t-1 to the
//   512-dim output (2 floats/thread, basis in registers) — independent work
//   that fills the scan's ~49% idle issue slots. Epilogue handles t=127.

#define SS 128
#define VV 512
#define NROWS 208      // 8 pop + 8 pushop + 128 pushfn + 64 calc
#define ZOFF 1e-6f

// ws layout (float offsets)
#define OFF_I0   0                          // interp0: 32768*208
#define OFF_OC   (32768*208)                // (unused since R15 — kept for layout)
#define OFF_GI   (OFF_OC + 32768*32)        // G[2][32][208]  (stack, basis, row)
#define OFF_M    (OFF_GI + 2*32*208)        // Gram 32*32
#define OFF_A    (OFF_M + 1024)             // A coef 208*3
#define OFF_Bc   (OFF_A + 624)              // B coef 208*3
#define OFF_W0   (OFF_Bc + 624)             // Wh/Wl f16: 2 x [208][512] halves

typedef _Float16 half8 __attribute__((ext_vector_type(8)));
typedef float f32x4 __attribute__((ext_vector_type(4)));
typedef float f32x2 __attribute__((ext_vector_type(2)));

__device__ __forceinline__ float rlane(float v, int lane) {
    return __int_as_float(__builtin_amdgcn_readlane(__float_as_int(v), lane));
}
template <int CTRL>
__device__ __forceinline__ float dpp_add(float x) {
    int y = __builtin_amdgcn_update_dpp(0, __float_as_int(x), CTRL, 0xF, 0xF, true);
    return x + __int_as_float(y);
}
// full 16-lane row sum, result in all lanes of the row (pure VALU)
__device__ __forceinline__ float sum16(float x) {
    x = dpp_add<0xB1>(x);    // quad_perm [1,0,3,2]  (xor 1)
    x = dpp_add<0x4E>(x);    // quad_perm [2,3,0,1]  (xor 2)
    x = dpp_add<0x124>(x);   // row_ror:4
    x = dpp_add<0x128>(x);   // row_ror:8
    return x;
}
__device__ __forceinline__ float swz16(float x) {   // lane ^ 16 within 32-group
    return __int_as_float(__builtin_amdgcn_ds_swizzle(__float_as_int(x), 0x401F));
}

__device__ __forceinline__ const float* w_row(int r, const float* pw, const float* pow_,
                                              const float* pfw, const float* cw) {
    if (r < 8)   return pw   + r * 1536;
    if (r < 16)  return pow_ + (r - 8) * 1536;
    if (r < 144) return pfw  + (r - 16) * 1536;
    return cw + (r - 144) * 1536;
}
__device__ __forceinline__ const float* nw_row(int r, const float* pn, const float* pon,
                                               const float* pfn, const float* cn) {
    if (r < 8)   return pn   + r * 3;
    if (r < 16)  return pon  + (r - 8) * 3;
    if (r < 144) return pfn  + (r - 16) * 3;
    return cn + (r - 144) * 3;
}

// ---------------- kernel B: precompute tables ----------------
__global__ void kB(const float* __restrict__ syms, const float* __restrict__ siv,
                   const float* __restrict__ pw, const float* __restrict__ pn,
                   const float* __restrict__ pow_, const float* __restrict__ pon,
                   const float* __restrict__ pfw, const float* __restrict__ pfn,
                   const float* __restrict__ cw, const float* __restrict__ cn,
                   float* __restrict__ ws) {
    int blk = blockIdx.x, tid = threadIdx.x;
    if (blk < 64) {
        // G[jj][e][c] = basis_e . w_row(c)[(jj+1)*512 ..)
        int jj = blk >> 5, e = blk & 31;
        __shared__ float bas[512];
        for (int i = tid; i < 512; i += 256)
            bas[i] = (e == 0) ? 1.0f : ((e == 1) ? siv[i] : syms[(e - 2) * 512 + i]);
        __syncthreads();
        if (tid < NROWS) {
            int c = tid;
            const float4* w4 = (const float4*)(w_row(c, pw, pow_, pfw, cw) + (jj + 1) * 512);
            const float4* b4 = (const float4*)bas;
            float s = 0.f;
            for (int q = 0; q < 128; ++q) {
                float4 a = b4[q], b = w4[q];
                s += a.x * b.x + a.y * b.y + a.z * b.z + a.w * b.w;
            }
            ws[OFF_GI + (jj * 32 + e) * 208 + c] = s;
        }
    } else if (blk == 64) {
        // Gram M[m][mm]
        __shared__ float basw[32 * 512];
        for (int i = tid; i < 32 * 512; i += 256) {
            int m = i >> 9, v = i & 511;
            basw[i] = (m == 0) ? 1.0f : ((m == 1) ? siv[v] : syms[(m - 2) * 512 + v]);
        }
        __syncthreads();
        for (int p = tid; p < 1024; p += 256) {
            int m = p >> 5, mm = p & 31;
            const float4* a4 = (const float4*)(basw + m * 512);
            const float4* b4 = (const float4*)(basw + mm * 512);
            float s = 0.f;
            for (int q = 0; q < 128; ++q) {
                float4 a = a4[q], b = b4[q];
                s += a.x * b.x + a.y * b.y + a.z * b.z + a.w * b.w;
            }
            ws[OFF_M + p] = s;
        }
    } else if (blk == 65) {
        // folded NAND coefs: A=(2*sig-1)/||w||, B=1-sig   for (r, j)
        for (int idx = tid; idx < 624; idx += 256) {
            int r = idx / 3, j = idx % 3;
            const float4* w4 = (const float4*)(w_row(r, pw, pow_, pfw, cw) + j * 512);
            float s = 0.f;
            for (int q = 0; q < 128; ++q) {
                float4 b = w4[q];
                s += b.x * b.x + b.y * b.y + b.z * b.z + b.w * b.w;
            }
            float nrm = fmaxf(sqrtf(s), 1e-8f);
            float nwv = nw_row(r, pn, pon, pfn, cn)[j];
            float sig = 1.f / (1.f + expf(-nwv));
            ws[OFF_A + idx]  = (2.f * sig - 1.f) / nrm;
            ws[OFF_Bc + idx] = 1.f - sig;
        }
    } else {
        // gather w j=0 slice as split-f16 hi/lo: Wh/Wl [208][512] halves — 16 blocks
        int part = blk - 66;
        _Float16* whp = (_Float16*)(ws + OFF_W0);
        _Float16* wlp = whp + 208 * 512;
        for (int i = tid; i < 6656; i += 256) {
            int flat = part * 6656 + i;
            int c = flat >> 9, v = flat & 511;
            float wv = w_row(c, pw, pow_, pfw, cw)[v];
            _Float16 h = (_Float16)wv;
            whp[flat] = h;
            wlp[flat] = (_Float16)(wv - (float)h);
        }
    }
}

// ---------------- kernel A: interp0 via split-f16 MFMA GEMM ----------------
// grid = 1024: bid>>1 = row-block (64 rows), bid&1 = col-half. Global wave id
// gw = (bid&1)*4+wid in [0,8) takes tiles {2,2,2,2,2,1,1,1} of the 13 col-tiles.
__global__ __launch_bounds__(256) void kA(const float* __restrict__ x, float* __restrict__ ws) {
    __shared__ half8 AH[2][256];   // [buf][mfrag*64 + fraglane]
    __shared__ half8 AL[2][256];
    __shared__ float red[256];
    __shared__ float invx[64];
    const int tid = threadIdx.x;
    const int wid = tid >> 6, l = tid & 63;
    const int bid = blockIdx.x;
    const size_t bt0 = (size_t)(bid >> 1) * 64;

    const int sr = tid >> 2, ss = tid & 3;
    const float* xp = x + (bt0 + sr) * 512 + ss * 8;
    const int wpos = (sr >> 4) * 64 + (sr & 15) + (ss << 4);   // frag slot

    const _Float16* whp = (const _Float16*)(ws + OFF_W0);
    const _Float16* wlp = whp + 208 * 512;

    const int gw = ((bid & 1) << 2) | wid;           // 0..7
    const int nt = (gw < 5) ? 2 : 1;
    const int t0 = (gw < 5) ? (2 * gw) : (5 + gw);   // tiles 0..9 / 10,11,12

    f32x4 acc[4][2];
#pragma unroll
    for (int m = 0; m < 4; ++m)
#pragma unroll
        for (int tt = 0; tt < 2; ++tt)
            acc[m][tt] = (f32x4){0.f, 0.f, 0.f, 0.f};

    float sumsq = 0.f;

    // prologue stage of kt=0
    {
        float v[8];
        *(float4*)v       = *(const float4*)(xp);
        *(float4*)(v + 4) = *(const float4*)(xp + 4);
        half8 hh, hl;
#pragma unroll
        for (int j = 0; j < 8; ++j) {
            sumsq += v[j] * v[j];
            _Float16 h = (_Float16)v[j];
            hh[j] = h;
            hl[j] = (_Float16)(v[j] - (float)h);
        }
        AH[0][wpos] = hh;
        AL[0][wpos] = hl;
    }
    __syncthreads();

    for (int kt = 0; kt < 16; ++kt) {
        const int buf = kt & 1;
        half8 ahm[4], alm[4];
#pragma unroll
        for (int m = 0; m < 4; ++m) {
            ahm[m] = AH[buf][m * 64 + l];
            alm[m] = AL[buf][m * 64 + l];
        }
        float4 xv0, xv1;
        if (kt < 15) {
            xv0 = *(const float4*)(xp + (kt + 1) * 32);
            xv1 = *(const float4*)(xp + (kt + 1) * 32 + 4);
        }
        const int kof = kt * 32 + (l >> 4) * 8;
#pragma unroll
        for (int tt = 0; tt < 2; ++tt) {
            if (tt < nt) {
                const int c = (t0 + tt) * 16 + (l & 15);
                half8 bh = *(const half8*)(whp + c * 512 + kof);
                half8 bl = *(const half8*)(wlp + c * 512 + kof);
#pragma unroll
                for (int m = 0; m < 4; ++m) {
                    acc[m][tt] = __builtin_amdgcn_mfma_f32_16x16x32_f16(ahm[m], bh, acc[m][tt], 0, 0, 0);
                    acc[m][tt] = __builtin_amdgcn_mfma_f32_16x16x32_f16(ahm[m], bl, acc[m][tt], 0, 0, 0);
                    acc[m][tt] = __builtin_amdgcn_mfma_f32_16x16x32_f16(alm[m], bh, acc[m][tt], 0, 0, 0);
                }
            }
        }
        if (kt < 15) {
            float v[8];
            *(float4*)v = xv0; *(float4*)(v + 4) = xv1;
            half8 hh, hl;
#pragma unroll
            for (int j = 0; j < 8; ++j) {
                sumsq += v[j] * v[j];
                _Float16 h = (_Float16)v[j];
                hh[j] = h;
                hl[j] = (_Float16)(v[j] - (float)h);
            }
            AH[buf ^ 1][wpos] = hh;
            AL[buf ^ 1][wpos] = hl;
        }
        __syncthreads();
    }

    red[tid] = sumsq;
    __syncthreads();
    if (tid < 64) {
        float s = red[tid * 4] + red[tid * 4 + 1] + red[tid * 4 + 2] + red[tid * 4 + 3];
        invx[tid] = 1.f / fmaxf(sqrtf(s), 1e-8f);
    }
    __syncthreads();

    // epilogue: interp0 = A0*|dot|*invx + B0.  D frag: col=lane&15, row=(lane>>4)*4+reg
#pragma unroll
    for (int tt = 0; tt < 2; ++tt) {
        if (tt < nt) {
            const int c = (t0 + tt) * 16 + (l & 15);
            const float A0 = ws[OFF_A + c * 3];
            const float B0 = ws[OFF_Bc + c * 3];
#pragma unroll
            for (int m = 0; m < 4; ++m) {
                const int rbase = m * 16 + (l >> 4) * 4;
#pragma unroll
                for (int j = 0; j < 4; ++j) {
                    const float ix = invx[rbase + j];
                    ws[OFF_I0 + (bt0 + rbase + j) * 208 + c] = A0 * fabsf(acc[m][tt][j]) * ix + B0;
                }
            }
        }
    }
}

// ---------------- kernel C: serial scan + fused output expansion (kD deleted) ----------------
// Every thread owns row r = (wid==3)? 144+l : tid. Readlane gather + packed
// f32x2 FMA chains (R14). wave3 publishes oc(t) to ocL[t&1]; during step t all
// threads expand oc(t-1) -> out[(b,t-1), 512] (2 floats/thread, basis in regs).
__global__ __attribute__((amdgpu_flat_work_group_size(256, 256), amdgpu_waves_per_eu(1, 1)))
void kC(float* __restrict__ ws, const float* __restrict__ sharp,
        const float* __restrict__ syms, const float* __restrict__ siv,
        float* __restrict__ out) {
    __shared__ float nndL[2][144];
    __shared__ float ocL[2][32];
    const int b = blockIdx.x, tid = threadIdx.x;
    const int wid = tid >> 6, l = tid & 63;
    const int k = l >> 5, m = l & 31;
    const int isW3 = (wid == 3);
    const int isRow = (tid < 144);
    const int r = isW3 ? (144 + l) : tid;          // owned NAND row

    const float* GI = ws + OFF_GI;
    // interleaved tables: GM1[i] = {G1[i], M[m][i]}, GM2[i] = {G2[i], M[m][i]}
    f32x2 GM1[32], GM2[32];
#pragma unroll
    for (int i = 0; i < 32; ++i) {
        float mv = ws[OFF_M + m * 32 + i];
        GM1[i] = (f32x2){GI[i * 208 + r], mv};
        GM2[i] = (f32x2){GI[(32 + i) * 208 + r], mv};
    }
    const float A1 = ws[OFF_A + r * 3 + 1],  A2 = ws[OFF_A + r * 3 + 2];
    const float B1 = ws[OFF_Bc + r * 3 + 1], B2 = ws[OFF_Bc + r * 3 + 2];
    const float sh = sharp[k];

    // fused-output basis: this thread's 2 output coords (vc = 2*tid)
    float2 sv2 = *(const float2*)(siv + 2 * tid);
    float2 sy[30];
#pragma unroll
    for (int mm = 0; mm < 30; ++mm)
        sy[mm] = *(const float2*)(syms + mm * 512 + 2 * tid);
    float* outb = out + (size_t)b * SS * 512 + 2 * tid;

    // replicated stack state
    float st[4], p[4];
#pragma unroll
    for (int d = 0; d < 4; ++d) {
        st[d] = (d == 1) ? ((m == 1) ? 1.f : 0.f) : ((m == 0) ? ZOFF : 0.f);
        p[d] = (d == 1) ? 1.f : 0.f;
    }
    float pk = st[0] * p[0] + st[1] * p[1] + st[2] * p[2] + st[3] * p[3];
    float pkOther = __shfl_xor(pk, 32);

    const float* i0base = ws + OFF_I0 + (size_t)b * SS * 208;
    const int ioff = isW3 ? 0 : 1;                 // rows consume i0(t+1), w3 i0(t)
    float i0pro = i0base[r];                       // i0(0) for prologue
    float i0use = i0base[(size_t)ioff * 208 + r];  // rows: i0(1), w3: i0(0)

    // CA: readlane gather; packed f32x2 FMA chains {dot, gram} sharing v0/v1
    auto CA = [&](float pp, float po, float iv) -> float {
        f32x2 a1 = (f32x2){0.f, 0.f}, b1 = (f32x2){0.f, 0.f};
        f32x2 a2 = (f32x2){0.f, 0.f}, b2 = (f32x2){0.f, 0.f};
#pragma unroll
        for (int mm = 0; mm < 32; ++mm) {
            float v0 = rlane(pp, mm);        // pk0[mm]
            float v1 = rlane(pp, 32 + mm);   // pk1[mm]
            if (mm & 1) { b1 += GM1[mm] * v0;  b2 += GM2[mm] * v1; }
            else        { a1 += GM1[mm] * v0;  a2 += GM2[mm] * v1; }
        }
        float dd1 = a1.x + b1.x, gq0 = a1.y + b1.y;
        float dd2 = a2.x + b2.x, gq1 = a2.y + b2.y;
        float pm0 = (k ? po : pp) * gq0;
        float pm1 = (k ? pp : po) * gq1;
        float q0 = sum16(pm0); q0 += swz16(q0);
        float q1 = sum16(pm1); q1 += swz16(q1);
        float iq0 = __frsqrt_rn(fmaxf(q0, 1e-16f));
        float iq1 = __frsqrt_rn(fmaxf(q1, 1e-16f));
        return iv * (A1 * fabsf(dd1) * iq0 + B1) * (A2 * fabsf(dd2) * iq1 + B2);
    };
    // expand ocL[buf] -> out row t (2 floats/thread); independent filler work
    auto expand = [&](int buf, int t) {
        const float* ocp = ocL[buf];
        float4 c[8];
#pragma unroll
        for (int q = 0; q < 8; ++q) c[q] = *(const float4*)(ocp + 4 * q);
        float o0 = c[0].x + c[0].y * sv2.x;
        float o1 = c[0].x + c[0].y * sv2.y;
#pragma unroll
        for (int mm = 0; mm < 30; ++mm) {
            float cv = (mm + 2 < 4) ? ((mm + 2 == 2) ? c[0].z : c[0].w)
                                    : ((&c[0].x)[mm + 2]);
            o0 += cv * sy[mm].x;
            o1 += cv * sy[mm].y;
        }
        *(float2*)(outb + (size_t)t * 512) = (float2){o0, o1};
    };

    // ---- prologue: nnd(0) -> nndL[0] ----
    {
        float nv0 = CA(pk, pkOther, i0pro);
        if (isRow) nndL[0][tid] = nv0;
    }
    __syncthreads();

    for (int t = 0; t < SS; ++t) {
        int nidx = t + 1 + ioff; if (nidx > SS - 1) nidx = SS - 1;
        float i0nxt = i0base[(size_t)nidx * 208 + r];

        const float* nb = nndL[t & 1];
        // ---- gates + push_val + state update (replicated in all waves) ----
        float4 gp4 = *(const float4*)(nb + 4 * k);
        float4 gq4 = *(const float4*)(nb + 8 + 4 * k);
        float prp0 = 1.f / (1.f + __expf((fmaxf(gp4.z, gp4.w) - fmaxf(gp4.x, gp4.y)) * sh));
        float prq0 = 1.f / (1.f + __expf((fmaxf(gq4.z, gq4.w) - fmaxf(gq4.x, gq4.y)) * sh));
        float prp1 = 1.f - prp0, prq1 = 1.f - prq0;
        float prx = 0.f, pry = 0.f;
        if (m >= 2) {
            float2 pr2 = *(const float2*)(nb + 16 + 64 * k + 2 * m - 4);
            prx = pr2.x; pry = pr2.y;
        }
        float4 t30 = *(const float4*)(nb + 16 + 64 * k + 60);
        float pk0m = k ? pkOther : pk;
        float pk1m = k ? pk : pkOther;
        float pvc = prx + pry + (t30.x + t30.y) * pk0m + (t30.z + t30.w) * pk1m;

        float zc = (m == 0) ? ZOFF : 0.f;
        float s1v[4], p1[4];
#pragma unroll
        for (int d = 0; d < 4; ++d) {
            float ps = st[d] * (1.f - p[d]) + zc * p[d];
            s1v[d] = ps * prp0 + st[d] * prp1;
            p1[d] = p[(d + 1) & 3] * prp0 + p[d] * prp1;
        }
#pragma unroll
        for (int d = 0; d < 4; ++d) {
            float pu = p1[(d + 3) & 3];
            float su = s1v[d] * (1.f - pu) + pvc * pu;
            st[d] = su * prq0 + s1v[d] * prq1;
            p[d] = pu * prq0 + p1[d] * prq1;
        }
        float pkp = st[0] * p[0] + st[1] * p[1] + st[2] * p[2] + st[3] * p[3];
        float pkpOth = __shfl_xor(pkp, 32);

        // ---- fused output for step t-1 (independent; fills stall slots) ----
        if (t > 0) expand((t - 1) & 1, t - 1);

        // ---- fused gram + dots + nnd ----
        float nv = CA(pkp, pkpOth, i0use);
        if (isRow) nndL[(t + 1) & 1][tid] = nv;
        if (isW3) {
            // out coords via lane ops over per-lane nnd2 (calc row 144+lane)
            float s60 = rlane(nv, 60), s61 = rlane(nv, 61);
            float s62 = rlane(nv, 62), s63 = rlane(nv, 63);
            int src = (m >= 2) ? (2 * m - 4) : 0;
            float cx = __shfl(nv, src);
            float cy = __shfl(nv, src + 1);
            if (m < 2) { cx = 0.f; cy = 0.f; }
            if (l < 32) {
                float oc = cx + cy + (s60 + s61) * pkp + (s62 + s63) * pkpOth;
                ocL[t & 1][m] = oc;
            }
        }
        __syncthreads();   // nndL(t+1) + ocL(t) visible for next step
        pk = pkp;
        pkOther = pkpOth;
        i0use = i0nxt;
    }
    // epilogue: output for the final step (t = SS-1), ocL[(SS-1)&1]
    expand((SS - 1) & 1, SS - 1);
}

extern "C" void kernel_launch(void* const* d_in, const int* in_sizes, int n_in,
                              void* d_out, int out_size, void* d_ws, size_t ws_size,
                              hipStream_t stream) {
    const float* x    = (const float*)d_in[0];
    const float* syms = (const float*)d_in[1];
    const float* siv  = (const float*)d_in[2];
    const float* shp  = (const float*)d_in[3];
    const float* pw   = (const float*)d_in[4];
    const float* pn   = (const float*)d_in[5];
    const float* pow_ = (const float*)d_in[6];
    const float* pon  = (const float*)d_in[7];
    const float* pfw  = (const float*)d_in[8];
    const float* pfn  = (const float*)d_in[9];
    const float* cw   = (const float*)d_in[10];
    const float* cn   = (const float*)d_in[11];
    float* ws  = (float*)d_ws;
    float* out = (float*)d_out;

    hipLaunchKernelGGL(kB, dim3(82),   dim3(256), 0, stream,
                       syms, siv, pw, pn, pow_, pon, pfw, pfn, cw, cn, ws);
    hipLaunchKernelGGL(kA, dim3(1024), dim3(256), 0, stream, x, ws);
    hipLaunchKernelGGL(kC, dim3(256),  dim3(256), 0, stream, ws, shp, syms, siv, out);
}